// Round 6
// baseline (282.277 us; speedup 1.0000x reference)
//
#include <hip/hip_runtime.h>
#include <math.h>

#define NPTS   131072
#define INF    512
#define ROWF   513      // 512 features + 1 cid column
#define NCASE  64
#define HID    512
#define NB     256      // histogram chunks
#define CHUNK  512      // points per chunk
#define SEG    16       // segments per case for k_sum

typedef float v4f __attribute__((ext_vector_type(4)));

// ---------------------------------------------------------------------------
// K_hist: per-chunk cid histogram (LDS int atomics -> deterministic) + cid cache.
// hist stored transposed: hist[c*NB + b].
// ---------------------------------------------------------------------------
__global__ __launch_bounds__(256)
void k_hist(const float* __restrict__ x, int* __restrict__ hist,
            int* __restrict__ cids) {
  __shared__ int h[NCASE];
  const int t = threadIdx.x;
  const int b = blockIdx.x;
  if (t < NCASE) h[t] = 0;
  __syncthreads();
  const int base = b * CHUNK;
  for (int i = t; i < CHUNK; i += 256) {
    float cf = x[(size_t)(base + i) * ROWF + INF];
    int c = (int)(cf + 0.5f);
    cids[base + i] = c;
    atomicAdd(&h[c], 1);
  }
  __syncthreads();
  if (t < NCASE) hist[t * NB + b] = h[t];
}

// ---------------------------------------------------------------------------
// K_scanbuild: merged scan+build. Block b, lane c streams hist row c:
// pref = count of case c in chunks < b, tot = total count of case c.
// base[c] via wave-scan of tot. Then deterministic in-order list emit.
// ---------------------------------------------------------------------------
__global__ __launch_bounds__(64)
void k_scanbuild(const int* __restrict__ hist, const int* __restrict__ cids,
                 int* __restrict__ idxlist, int* __restrict__ cnt) {
  __shared__ int cidl[CHUNK];
  const int lane = threadIdx.x;
  const int b = blockIdx.x;
  for (int i = lane; i < CHUNK; i += 64) cidl[i] = cids[b * CHUNK + i];
  const int* hrow = hist + lane * NB;
  int pref = 0, tot = 0;
  for (int bb = 0; bb < NB; ++bb) {
    int v = hrow[bb];
    pref += (bb < b) ? v : 0;
    tot  += v;
  }
  int sc = tot;
  for (int d = 1; d < 64; d <<= 1) {
    int u = __shfl_up(sc, d, 64);
    if (lane >= d) sc += u;
  }
  const int base = sc - tot;                // exclusive scan -> base[c]
  if (b == 0) cnt[lane] = tot;
  __syncthreads();
  int myoff = base + pref;
  int rank = 0;
  for (int i = 0; i < CHUNK; ++i) {
    if (cidl[i] == lane) { idxlist[myoff + rank] = b * CHUNK + i; ++rank; }
  }
}

// ---------------------------------------------------------------------------
// K_sum: gather-sum with register-broadcast indices (unchanged from R5-pass).
// ---------------------------------------------------------------------------
__global__ __launch_bounds__(128)
void k_sum(const float* __restrict__ x, const int* __restrict__ idxlist,
           const int* __restrict__ cnt, float* __restrict__ psum) {
  __shared__ float buf[2][HID];
  const int t = threadIdx.x;
  const int lane = t & 63;
  const int w = t >> 6;
  const int s = blockIdx.x;
  const int c = blockIdx.y;

  int lv = cnt[lane];
  int sc = lv;
  for (int d = 1; d < 64; d <<= 1) {
    int u = __shfl_up(sc, d, 64);
    if (lane >= d) sc += u;
  }
  const int bs = __shfl(sc - lv, c, 64);    // base[c]
  const int n  = __shfl(lv, c, 64);         // cnt[c]

  const int p0 = (s * n) / SEG;
  const int p1 = ((s + 1) * n) / SEG;
  const int m  = p1 - p0;

  float a[8];
  #pragma unroll
  for (int k = 0; k < 8; ++k) a[k] = 0.f;

  for (int j0 = w * 64; j0 < m; j0 += 128) {
    const int nb = (m - j0 < 64) ? (m - j0) : 64;
    int iv = (lane < nb) ? idxlist[bs + p0 + j0 + lane] : 0;
    int jj = 0;
    for (; jj + 4 <= nb; jj += 4) {
      float v[4][8];
      #pragma unroll
      for (int u = 0; u < 4; ++u) {
        int idx = __shfl(iv, jj + u, 64);
        const float* r = x + (size_t)idx * ROWF + lane;
        #pragma unroll
        for (int k = 0; k < 8; ++k) v[u][k] = __builtin_nontemporal_load(r + 64 * k);
      }
      #pragma unroll
      for (int u = 0; u < 4; ++u) {
        #pragma unroll
        for (int k = 0; k < 8; ++k) a[k] += v[u][k];
      }
    }
    for (; jj < nb; ++jj) {
      int idx = __shfl(iv, jj, 64);
      const float* r = x + (size_t)idx * ROWF + lane;
      #pragma unroll
      for (int k = 0; k < 8; ++k) a[k] += __builtin_nontemporal_load(r + 64 * k);
    }
  }

  #pragma unroll
  for (int k = 0; k < 8; ++k) buf[w][lane + 64 * k] = a[k];
  __syncthreads();
  float* od = psum + ((size_t)c * SEG + s) * HID;
  for (int f = t; f < HID; f += 128) od[f] = buf[0][f] + buf[1][f];
}

// ---------------------------------------------------------------------------
// K_scale2: scale[row] = g[row] / ||V[row]|| for both layers in one launch.
// ---------------------------------------------------------------------------
__global__ __launch_bounds__(256)
void k_scale2(const float* __restrict__ V0, const float* __restrict__ g0,
              const float* __restrict__ V1, const float* __restrict__ g1,
              float* __restrict__ scale0, float* __restrict__ scale1) {
  __shared__ float red[256];
  const int row = blockIdx.x;               // 0..1023
  const int t   = threadIdx.x;
  const bool first = row < 512;
  const int r = first ? row : row - 512;
  const float* vr = (first ? V0 : V1) + (size_t)r * HID;
  float s = 0.f;
  for (int k = t; k < HID; k += 256) { float v = vr[k]; s += v * v; }
  red[t] = s;
  __syncthreads();
  for (int w = 128; w > 0; w >>= 1) {
    if (t < w) red[t] += red[t + w];
    __syncthreads();
  }
  if (t == 0) {
    float g = first ? g0[r] : g1[r];
    (first ? scale0 : scale1)[r] = g / sqrtf(red[0]);
  }
}

// ---------------------------------------------------------------------------
// K_mlp: fused psum-reduce + 3 layers for one case per block (case-local chain).
// LDS ping-pong ha/hb; 512 threads = one output element each per layer.
// ---------------------------------------------------------------------------
__global__ __launch_bounds__(512)
void k_mlp(const float* __restrict__ psum, const int* __restrict__ cnt,
           const float* __restrict__ V0, const float* __restrict__ scale0,
           const float* __restrict__ b0,
           const float* __restrict__ V1, const float* __restrict__ scale1,
           const float* __restrict__ b1,
           const float* __restrict__ Wf, const float* __restrict__ bf,
           float* __restrict__ h3) {
  __shared__ float ha[HID], hb[HID];
  const int n = blockIdx.x;
  const int o = threadIdx.x;
  float inv = 1.f / fmaxf((float)cnt[n], 1.f);
  float s = 0.f;
  for (int seg = 0; seg < SEG; ++seg)
    s += psum[((size_t)n * SEG + seg) * HID + o];
  ha[o] = s * inv;
  __syncthreads();
  {                                         // layer 0: ha -> hb (silu)
    const float* wr = V0 + (size_t)o * HID;
    float s0 = 0.f, s1 = 0.f, s2 = 0.f, s3 = 0.f;
    for (int k = 0; k < HID; k += 4) {
      float4 h4 = *(const float4*)&ha[k];
      float4 w4 = *(const float4*)&wr[k];
      s0 += h4.x * w4.x; s1 += h4.y * w4.y;
      s2 += h4.z * w4.z; s3 += h4.w * w4.w;
    }
    float y = ((s0 + s1) + (s2 + s3)) * scale0[o] + b0[o];
    hb[o] = y / (1.f + expf(-y));
  }
  __syncthreads();
  {                                         // layer 1: hb -> ha (silu)
    const float* wr = V1 + (size_t)o * HID;
    float s0 = 0.f, s1 = 0.f, s2 = 0.f, s3 = 0.f;
    for (int k = 0; k < HID; k += 4) {
      float4 h4 = *(const float4*)&hb[k];
      float4 w4 = *(const float4*)&wr[k];
      s0 += h4.x * w4.x; s1 += h4.y * w4.y;
      s2 += h4.z * w4.z; s3 += h4.w * w4.w;
    }
    float y = ((s0 + s1) + (s2 + s3)) * scale1[o] + b1[o];
    ha[o] = y / (1.f + expf(-y));
  }
  __syncthreads();
  {                                         // layer 2: ha -> h3 (linear)
    const float* wr = Wf + (size_t)o * HID;
    float s0 = 0.f, s1 = 0.f, s2 = 0.f, s3 = 0.f;
    for (int k = 0; k < HID; k += 4) {
      float4 h4 = *(const float4*)&ha[k];
      float4 w4 = *(const float4*)&wr[k];
      s0 += h4.x * w4.x; s1 += h4.y * w4.y;
      s2 += h4.z * w4.z; s3 += h4.w * w4.w;
    }
    h3[(size_t)n * HID + o] = (s0 + s1) + (s2 + s3) + bf[o];
  }
}

// ---------------------------------------------------------------------------
// K_scatter: natural-order broadcast; each WAVE owns 32 contiguous rows ->
// perfectly sequential 64 KB nontemporal store stream per wave.
// ---------------------------------------------------------------------------
__global__ __launch_bounds__(256)
void k_scatter(const int* __restrict__ cids, const float* __restrict__ h3,
               float* __restrict__ out) {
  __shared__ int cl[128];
  const int t = threadIdx.x;
  const int lane = t & 63;
  const int w = t >> 6;                     // wave 0..3
  const int base = blockIdx.x * 128;
  if (t < 128) cl[t] = cids[base + t];
  __syncthreads();
  #pragma unroll 8
  for (int i = 0; i < 64; ++i) {
    const int r = w * 32 + (i >> 1);
    const int h = i & 1;
    const int c = cl[r];
    v4f hv = *((const v4f*)(h3 + (size_t)c * HID + h * 256) + lane);
    v4f* dst = (v4f*)(out + (size_t)(base + r) * HID + h * 256) + lane;
    __builtin_nontemporal_store(hv, dst);
  }
}

// ---------------------------------------------------------------------------
extern "C" void kernel_launch(void* const* d_in, const int* in_sizes, int n_in,
                              void* d_out, int out_size, void* d_ws, size_t ws_size,
                              hipStream_t stream) {
  const float* x  = (const float*)d_in[0];
  const float* V0 = (const float*)d_in[1];
  const float* g0 = (const float*)d_in[2];
  const float* b0 = (const float*)d_in[3];
  const float* V1 = (const float*)d_in[4];
  const float* g1 = (const float*)d_in[5];
  const float* b1 = (const float*)d_in[6];
  const float* Wf = (const float*)d_in[7];
  const float* bf = (const float*)d_in[8];
  float* out = (float*)d_out;
  float* ws  = (float*)d_ws;

  size_t off = 0;
  float* psum   = ws + off; off += (size_t)NCASE * SEG * HID;
  float* h3     = ws + off; off += NCASE * HID;
  float* scale0 = ws + off; off += 512;
  float* scale1 = ws + off; off += 512;
  int* iws = (int*)(ws + off);
  size_t ioff = 0;
  int* hist    = iws + ioff; ioff += NCASE * NB;
  int* cnt     = iws + ioff; ioff += NCASE;
  int* cids    = iws + ioff; ioff += NPTS;
  int* idxlist = iws + ioff; ioff += NPTS;

  k_hist     <<<dim3(NB), dim3(256), 0, stream>>>(x, hist, cids);
  k_scanbuild<<<dim3(NB), dim3(64), 0, stream>>>(hist, cids, idxlist, cnt);
  k_sum      <<<dim3(SEG, NCASE), dim3(128), 0, stream>>>(x, idxlist, cnt, psum);
  // INSTRUMENTATION: duplicate launch (idempotent). dur delta vs next round
  // (which removes it) = exact k_sum cost.
  k_sum      <<<dim3(SEG, NCASE), dim3(128), 0, stream>>>(x, idxlist, cnt, psum);
  k_scale2   <<<dim3(1024), dim3(256), 0, stream>>>(V0, g0, V1, g1, scale0, scale1);
  k_mlp      <<<dim3(NCASE), dim3(512), 0, stream>>>(psum, cnt, V0, scale0, b0,
                                                     V1, scale1, b1, Wf, bf, h3);
  k_scatter  <<<dim3(NPTS / 128), dim3(256), 0, stream>>>(cids, h3, out);
}

// Round 7
// 242.862 us; speedup vs baseline: 1.1623x; 1.1623x over previous
//
#include <hip/hip_runtime.h>
#include <math.h>

#define NPTS   131072
#define INF    512
#define ROWF   513      // 512 features + 1 cid column
#define NCASE  64
#define HID    512
#define NB     256      // histogram chunks
#define CHUNK  512      // points per chunk
#define SEG    64       // segments per case for k_sum

typedef float v4f __attribute__((ext_vector_type(4)));

// ---------------------------------------------------------------------------
// K_hist: per-chunk cid histogram (LDS int atomics -> deterministic) + cid cache.
// hist stored transposed: hist[c*NB + b].
// ---------------------------------------------------------------------------
__global__ __launch_bounds__(256)
void k_hist(const float* __restrict__ x, int* __restrict__ hist,
            int* __restrict__ cids) {
  __shared__ int h[NCASE];
  const int t = threadIdx.x;
  const int b = blockIdx.x;
  if (t < NCASE) h[t] = 0;
  __syncthreads();
  const int base = b * CHUNK;
  for (int i = t; i < CHUNK; i += 256) {
    float cf = x[(size_t)(base + i) * ROWF + INF];
    int c = (int)(cf + 0.5f);
    cids[base + i] = c;
    atomicAdd(&h[c], 1);
  }
  __syncthreads();
  if (t < NCASE) hist[t * NB + b] = h[t];
}

// ---------------------------------------------------------------------------
// K_scanbuild: merged scan+build. Block b, lane c streams hist row c:
// pref = count of case c in chunks < b, tot = total count of case c.
// base[c] via wave-scan of tot. Then deterministic in-order list emit.
// ---------------------------------------------------------------------------
__global__ __launch_bounds__(64)
void k_scanbuild(const int* __restrict__ hist, const int* __restrict__ cids,
                 int* __restrict__ idxlist, int* __restrict__ cnt) {
  __shared__ int cidl[CHUNK];
  const int lane = threadIdx.x;
  const int b = blockIdx.x;
  for (int i = lane; i < CHUNK; i += 64) cidl[i] = cids[b * CHUNK + i];
  const int* hrow = hist + lane * NB;
  int pref = 0, tot = 0;
  for (int bb = 0; bb < NB; ++bb) {
    int v = hrow[bb];
    pref += (bb < b) ? v : 0;
    tot  += v;
  }
  int sc = tot;
  for (int d = 1; d < 64; d <<= 1) {
    int u = __shfl_up(sc, d, 64);
    if (lane >= d) sc += u;
  }
  const int base = sc - tot;                // exclusive scan -> base[c]
  if (b == 0) cnt[lane] = tot;
  __syncthreads();
  int myoff = base + pref;
  int rank = 0;
  for (int i = 0; i < CHUNK; ++i) {
    if (cidl[i] == lane) { idxlist[myoff + rank] = b * CHUNK + i; ++rank; }
  }
}

// ---------------------------------------------------------------------------
// K_sum v2: one WAVE per (segment, case); ~32 points per segment.
// No LDS: thread-private accumulators, direct psum write.
// 8 points per group -> 64 independent 256B loads in flight per wave;
// occupancy 16 blocks/CU (grid 4096) supplies the TLP to hide HBM latency.
// ---------------------------------------------------------------------------
__global__ __launch_bounds__(64)
void k_sum(const float* __restrict__ x, const int* __restrict__ idxlist,
           const int* __restrict__ cnt, float* __restrict__ psum) {
  const int lane = threadIdx.x;
  const int s = blockIdx.x;
  const int c = blockIdx.y;

  int lv = cnt[lane];
  int sc = lv;
  for (int d = 1; d < 64; d <<= 1) {
    int u = __shfl_up(sc, d, 64);
    if (lane >= d) sc += u;
  }
  const int bs = __shfl(sc - lv, c, 64);    // base[c]
  const int n  = __shfl(lv, c, 64);         // cnt[c]

  const int p0 = (s * n) / SEG;
  const int p1 = ((s + 1) * n) / SEG;
  const int m  = p1 - p0;

  float a[8];
  #pragma unroll
  for (int k = 0; k < 8; ++k) a[k] = 0.f;

  for (int j0 = 0; j0 < m; j0 += 64) {
    const int nb = (m - j0 < 64) ? (m - j0) : 64;
    int iv = (lane < nb) ? idxlist[bs + p0 + j0 + lane] : 0;
    int jj = 0;
    for (; jj + 8 <= nb; jj += 8) {
      float v[8][8];
      #pragma unroll
      for (int u = 0; u < 8; ++u) {
        int idx = __shfl(iv, jj + u, 64);
        const float* r = x + (size_t)idx * ROWF + lane;
        #pragma unroll
        for (int k = 0; k < 8; ++k) v[u][k] = __builtin_nontemporal_load(r + 64 * k);
      }
      #pragma unroll
      for (int u = 0; u < 8; ++u) {
        #pragma unroll
        for (int k = 0; k < 8; ++k) a[k] += v[u][k];
      }
    }
    for (; jj < nb; ++jj) {
      int idx = __shfl(iv, jj, 64);
      const float* r = x + (size_t)idx * ROWF + lane;
      #pragma unroll
      for (int k = 0; k < 8; ++k) a[k] += __builtin_nontemporal_load(r + 64 * k);
    }
  }

  float* od = psum + ((size_t)c * SEG + s) * HID;
  #pragma unroll
  for (int k = 0; k < 8; ++k) od[lane + 64 * k] = a[k];
}

// ---------------------------------------------------------------------------
// K_scale2: scale[row] = g[row] / ||V[row]|| for both layers in one launch.
// ---------------------------------------------------------------------------
__global__ __launch_bounds__(256)
void k_scale2(const float* __restrict__ V0, const float* __restrict__ g0,
              const float* __restrict__ V1, const float* __restrict__ g1,
              float* __restrict__ scale0, float* __restrict__ scale1) {
  __shared__ float red[256];
  const int row = blockIdx.x;               // 0..1023
  const int t   = threadIdx.x;
  const bool first = row < 512;
  const int r = first ? row : row - 512;
  const float* vr = (first ? V0 : V1) + (size_t)r * HID;
  float s = 0.f;
  for (int k = t; k < HID; k += 256) { float v = vr[k]; s += v * v; }
  red[t] = s;
  __syncthreads();
  for (int w = 128; w > 0; w >>= 1) {
    if (t < w) red[t] += red[t + w];
    __syncthreads();
  }
  if (t == 0) {
    float g = first ? g0[r] : g1[r];
    (first ? scale0 : scale1)[r] = g / sqrtf(red[0]);
  }
}

// ---------------------------------------------------------------------------
// K_mlp: fused psum-reduce + 3 layers for one case per block (case-local chain).
// ---------------------------------------------------------------------------
__global__ __launch_bounds__(512)
void k_mlp(const float* __restrict__ psum, const int* __restrict__ cnt,
           const float* __restrict__ V0, const float* __restrict__ scale0,
           const float* __restrict__ b0,
           const float* __restrict__ V1, const float* __restrict__ scale1,
           const float* __restrict__ b1,
           const float* __restrict__ Wf, const float* __restrict__ bf,
           float* __restrict__ h3) {
  __shared__ float ha[HID], hb[HID];
  const int n = blockIdx.x;
  const int o = threadIdx.x;
  float inv = 1.f / fmaxf((float)cnt[n], 1.f);
  float s = 0.f;
  for (int seg = 0; seg < SEG; ++seg)
    s += psum[((size_t)n * SEG + seg) * HID + o];
  ha[o] = s * inv;
  __syncthreads();
  {                                         // layer 0: ha -> hb (silu)
    const float* wr = V0 + (size_t)o * HID;
    float s0 = 0.f, s1 = 0.f, s2 = 0.f, s3 = 0.f;
    for (int k = 0; k < HID; k += 4) {
      float4 h4 = *(const float4*)&ha[k];
      float4 w4 = *(const float4*)&wr[k];
      s0 += h4.x * w4.x; s1 += h4.y * w4.y;
      s2 += h4.z * w4.z; s3 += h4.w * w4.w;
    }
    float y = ((s0 + s1) + (s2 + s3)) * scale0[o] + b0[o];
    hb[o] = y / (1.f + expf(-y));
  }
  __syncthreads();
  {                                         // layer 1: hb -> ha (silu)
    const float* wr = V1 + (size_t)o * HID;
    float s0 = 0.f, s1 = 0.f, s2 = 0.f, s3 = 0.f;
    for (int k = 0; k < HID; k += 4) {
      float4 h4 = *(const float4*)&hb[k];
      float4 w4 = *(const float4*)&wr[k];
      s0 += h4.x * w4.x; s1 += h4.y * w4.y;
      s2 += h4.z * w4.z; s3 += h4.w * w4.w;
    }
    float y = ((s0 + s1) + (s2 + s3)) * scale1[o] + b1[o];
    ha[o] = y / (1.f + expf(-y));
  }
  __syncthreads();
  {                                         // layer 2: ha -> h3 (linear)
    const float* wr = Wf + (size_t)o * HID;
    float s0 = 0.f, s1 = 0.f, s2 = 0.f, s3 = 0.f;
    for (int k = 0; k < HID; k += 4) {
      float4 h4 = *(const float4*)&ha[k];
      float4 w4 = *(const float4*)&wr[k];
      s0 += h4.x * w4.x; s1 += h4.y * w4.y;
      s2 += h4.z * w4.z; s3 += h4.w * w4.w;
    }
    h3[(size_t)n * HID + o] = (s0 + s1) + (s2 + s3) + bf[o];
  }
}

// ---------------------------------------------------------------------------
// K_scatter: natural-order broadcast; each WAVE owns 32 contiguous rows ->
// sequential 64 KB nontemporal store stream per wave.
// ---------------------------------------------------------------------------
__global__ __launch_bounds__(256)
void k_scatter(const int* __restrict__ cids, const float* __restrict__ h3,
               float* __restrict__ out) {
  __shared__ int cl[128];
  const int t = threadIdx.x;
  const int lane = t & 63;
  const int w = t >> 6;                     // wave 0..3
  const int base = blockIdx.x * 128;
  if (t < 128) cl[t] = cids[base + t];
  __syncthreads();
  #pragma unroll 8
  for (int i = 0; i < 64; ++i) {
    const int r = w * 32 + (i >> 1);
    const int h = i & 1;
    const int c = cl[r];
    v4f hv = *((const v4f*)(h3 + (size_t)c * HID + h * 256) + lane);
    v4f* dst = (v4f*)(out + (size_t)(base + r) * HID + h * 256) + lane;
    __builtin_nontemporal_store(hv, dst);
  }
}

// ---------------------------------------------------------------------------
extern "C" void kernel_launch(void* const* d_in, const int* in_sizes, int n_in,
                              void* d_out, int out_size, void* d_ws, size_t ws_size,
                              hipStream_t stream) {
  const float* x  = (const float*)d_in[0];
  const float* V0 = (const float*)d_in[1];
  const float* g0 = (const float*)d_in[2];
  const float* b0 = (const float*)d_in[3];
  const float* V1 = (const float*)d_in[4];
  const float* g1 = (const float*)d_in[5];
  const float* b1 = (const float*)d_in[6];
  const float* Wf = (const float*)d_in[7];
  const float* bf = (const float*)d_in[8];
  float* out = (float*)d_out;
  float* ws  = (float*)d_ws;

  size_t off = 0;
  float* psum   = ws + off; off += (size_t)NCASE * SEG * HID;   // 8 MB
  float* h3     = ws + off; off += NCASE * HID;
  float* scale0 = ws + off; off += 512;
  float* scale1 = ws + off; off += 512;
  int* iws = (int*)(ws + off);
  size_t ioff = 0;
  int* hist    = iws + ioff; ioff += NCASE * NB;
  int* cnt     = iws + ioff; ioff += NCASE;
  int* cids    = iws + ioff; ioff += NPTS;
  int* idxlist = iws + ioff; ioff += NPTS;

  k_hist     <<<dim3(NB), dim3(256), 0, stream>>>(x, hist, cids);
  k_scanbuild<<<dim3(NB), dim3(64), 0, stream>>>(hist, cids, idxlist, cnt);
  k_sum      <<<dim3(SEG, NCASE), dim3(64), 0, stream>>>(x, idxlist, cnt, psum);
  k_scale2   <<<dim3(1024), dim3(256), 0, stream>>>(V0, g0, V1, g1, scale0, scale1);
  k_mlp      <<<dim3(NCASE), dim3(512), 0, stream>>>(psum, cnt, V0, scale0, b0,
                                                     V1, scale1, b1, Wf, bf, h3);
  k_scatter  <<<dim3(NPTS / 128), dim3(256), 0, stream>>>(cids, h3, out);
}

// Round 8
// 238.808 us; speedup vs baseline: 1.1820x; 1.0170x over previous
//
#include <hip/hip_runtime.h>
#include <math.h>

#define NPTS   131072
#define INF    512
#define ROWF   513      // 512 features + 1 cid column
#define NCASE  64
#define HID    512
#define NB     256      // histogram chunks
#define CHUNK  512      // points per chunk
#define SEG    32       // segments per case for k_sum

typedef float v4f __attribute__((ext_vector_type(4)));

// ---------------------------------------------------------------------------
// K_hist: per-chunk cid histogram (LDS int atomics -> deterministic) + cid cache.
// hist stored transposed: hist[c*NB + b].
// ---------------------------------------------------------------------------
__global__ __launch_bounds__(256)
void k_hist(const float* __restrict__ x, int* __restrict__ hist,
            int* __restrict__ cids) {
  __shared__ int h[NCASE];
  const int t = threadIdx.x;
  const int b = blockIdx.x;
  if (t < NCASE) h[t] = 0;
  __syncthreads();
  const int base = b * CHUNK;
  for (int i = t; i < CHUNK; i += 256) {
    float cf = x[(size_t)(base + i) * ROWF + INF];
    int c = (int)(cf + 0.5f);
    cids[base + i] = c;
    atomicAdd(&h[c], 1);
  }
  __syncthreads();
  if (t < NCASE) hist[t * NB + b] = h[t];
}

// ---------------------------------------------------------------------------
// K_scanbuild: merged scan+build. Block b, lane c streams hist row c:
// pref = count of case c in chunks < b, tot = total count of case c.
// base[c] via wave-scan of tot. Then deterministic in-order list emit.
// ---------------------------------------------------------------------------
__global__ __launch_bounds__(64)
void k_scanbuild(const int* __restrict__ hist, const int* __restrict__ cids,
                 int* __restrict__ idxlist, int* __restrict__ cnt) {
  __shared__ int cidl[CHUNK];
  const int lane = threadIdx.x;
  const int b = blockIdx.x;
  for (int i = lane; i < CHUNK; i += 64) cidl[i] = cids[b * CHUNK + i];
  const int* hrow = hist + lane * NB;
  int pref = 0, tot = 0;
  for (int bb = 0; bb < NB; ++bb) {
    int v = hrow[bb];
    pref += (bb < b) ? v : 0;
    tot  += v;
  }
  int sc = tot;
  for (int d = 1; d < 64; d <<= 1) {
    int u = __shfl_up(sc, d, 64);
    if (lane >= d) sc += u;
  }
  const int base = sc - tot;                // exclusive scan -> base[c]
  if (b == 0) cnt[lane] = tot;
  __syncthreads();
  int myoff = base + pref;
  int rank = 0;
  for (int i = 0; i < CHUNK; ++i) {
    if (cidl[i] == lane) { idxlist[myoff + rank] = b * CHUNK + i; ++rank; }
  }
}

// ---------------------------------------------------------------------------
// K_sum: R5-proven structure (2-wave blocks, LDS combine), SEG=32 for 2x TLP.
// Each wave covers all 512 features (8/lane, stride-64 coalesced 256B loads);
// indices loaded once per 64-batch and __shfl-broadcast (no vmcnt drain).
// ---------------------------------------------------------------------------
__global__ __launch_bounds__(128)
void k_sum(const float* __restrict__ x, const int* __restrict__ idxlist,
           const int* __restrict__ cnt, float* __restrict__ psum) {
  __shared__ float buf[2][HID];
  const int t = threadIdx.x;
  const int lane = t & 63;
  const int w = t >> 6;
  const int s = blockIdx.x;
  const int c = blockIdx.y;

  int lv = cnt[lane];
  int sc = lv;
  for (int d = 1; d < 64; d <<= 1) {
    int u = __shfl_up(sc, d, 64);
    if (lane >= d) sc += u;
  }
  const int bs = __shfl(sc - lv, c, 64);    // base[c]
  const int n  = __shfl(lv, c, 64);         // cnt[c]

  const int p0 = (s * n) / SEG;
  const int p1 = ((s + 1) * n) / SEG;
  const int m  = p1 - p0;

  float a[8];
  #pragma unroll
  for (int k = 0; k < 8; ++k) a[k] = 0.f;

  for (int j0 = w * 64; j0 < m; j0 += 128) {
    const int nb = (m - j0 < 64) ? (m - j0) : 64;
    int iv = (lane < nb) ? idxlist[bs + p0 + j0 + lane] : 0;
    int jj = 0;
    for (; jj + 4 <= nb; jj += 4) {
      float v[4][8];
      #pragma unroll
      for (int u = 0; u < 4; ++u) {
        int idx = __shfl(iv, jj + u, 64);
        const float* r = x + (size_t)idx * ROWF + lane;
        #pragma unroll
        for (int k = 0; k < 8; ++k) v[u][k] = __builtin_nontemporal_load(r + 64 * k);
      }
      #pragma unroll
      for (int u = 0; u < 4; ++u) {
        #pragma unroll
        for (int k = 0; k < 8; ++k) a[k] += v[u][k];
      }
    }
    for (; jj < nb; ++jj) {
      int idx = __shfl(iv, jj, 64);
      const float* r = x + (size_t)idx * ROWF + lane;
      #pragma unroll
      for (int k = 0; k < 8; ++k) a[k] += __builtin_nontemporal_load(r + 64 * k);
    }
  }

  #pragma unroll
  for (int k = 0; k < 8; ++k) buf[w][lane + 64 * k] = a[k];
  __syncthreads();
  float* od = psum + ((size_t)c * SEG + s) * HID;
  for (int f = t; f < HID; f += 128) od[f] = buf[0][f] + buf[1][f];
}

// ---------------------------------------------------------------------------
// K_scale2: scale[row] = g[row] / ||V[row]|| for both layers in one launch.
// ---------------------------------------------------------------------------
__global__ __launch_bounds__(256)
void k_scale2(const float* __restrict__ V0, const float* __restrict__ g0,
              const float* __restrict__ V1, const float* __restrict__ g1,
              float* __restrict__ scale0, float* __restrict__ scale1) {
  __shared__ float red[256];
  const int row = blockIdx.x;               // 0..1023
  const int t   = threadIdx.x;
  const bool first = row < 512;
  const int r = first ? row : row - 512;
  const float* vr = (first ? V0 : V1) + (size_t)r * HID;
  float s = 0.f;
  for (int k = t; k < HID; k += 256) { float v = vr[k]; s += v * v; }
  red[t] = s;
  __syncthreads();
  for (int w = 128; w > 0; w >>= 1) {
    if (t < w) red[t] += red[t + w];
    __syncthreads();
  }
  if (t == 0) {
    float g = first ? g0[r] : g1[r];
    (first ? scale0 : scale1)[r] = g / sqrtf(red[0]);
  }
}

// ---------------------------------------------------------------------------
// K_mlp: fused psum-reduce + 3 layers for one case per block (case-local chain).
// ---------------------------------------------------------------------------
__global__ __launch_bounds__(512)
void k_mlp(const float* __restrict__ psum, const int* __restrict__ cnt,
           const float* __restrict__ V0, const float* __restrict__ scale0,
           const float* __restrict__ b0,
           const float* __restrict__ V1, const float* __restrict__ scale1,
           const float* __restrict__ b1,
           const float* __restrict__ Wf, const float* __restrict__ bf,
           float* __restrict__ h3) {
  __shared__ float ha[HID], hb[HID];
  const int n = blockIdx.x;
  const int o = threadIdx.x;
  float inv = 1.f / fmaxf((float)cnt[n], 1.f);
  float s = 0.f;
  for (int seg = 0; seg < SEG; ++seg)
    s += psum[((size_t)n * SEG + seg) * HID + o];
  ha[o] = s * inv;
  __syncthreads();
  {                                         // layer 0: ha -> hb (silu)
    const float* wr = V0 + (size_t)o * HID;
    float s0 = 0.f, s1 = 0.f, s2 = 0.f, s3 = 0.f;
    for (int k = 0; k < HID; k += 4) {
      float4 h4 = *(const float4*)&ha[k];
      float4 w4 = *(const float4*)&wr[k];
      s0 += h4.x * w4.x; s1 += h4.y * w4.y;
      s2 += h4.z * w4.z; s3 += h4.w * w4.w;
    }
    float y = ((s0 + s1) + (s2 + s3)) * scale0[o] + b0[o];
    hb[o] = y / (1.f + expf(-y));
  }
  __syncthreads();
  {                                         // layer 1: hb -> ha (silu)
    const float* wr = V1 + (size_t)o * HID;
    float s0 = 0.f, s1 = 0.f, s2 = 0.f, s3 = 0.f;
    for (int k = 0; k < HID; k += 4) {
      float4 h4 = *(const float4*)&hb[k];
      float4 w4 = *(const float4*)&wr[k];
      s0 += h4.x * w4.x; s1 += h4.y * w4.y;
      s2 += h4.z * w4.z; s3 += h4.w * w4.w;
    }
    float y = ((s0 + s1) + (s2 + s3)) * scale1[o] + b1[o];
    ha[o] = y / (1.f + expf(-y));
  }
  __syncthreads();
  {                                         // layer 2: ha -> h3 (linear)
    const float* wr = Wf + (size_t)o * HID;
    float s0 = 0.f, s1 = 0.f, s2 = 0.f, s3 = 0.f;
    for (int k = 0; k < HID; k += 4) {
      float4 h4 = *(const float4*)&ha[k];
      float4 w4 = *(const float4*)&wr[k];
      s0 += h4.x * w4.x; s1 += h4.y * w4.y;
      s2 += h4.z * w4.z; s3 += h4.w * w4.w;
    }
    h3[(size_t)n * HID + o] = (s0 + s1) + (s2 + s3) + bf[o];
  }
}

// ---------------------------------------------------------------------------
// K_scatter: R5-proven natural-order broadcast; nontemporal streaming stores.
// Each block owns 128 contiguous points; per iteration the block writes two
// full consecutive rows (4 KB contiguous).
// ---------------------------------------------------------------------------
__global__ __launch_bounds__(256)
void k_scatter(const int* __restrict__ cids, const float* __restrict__ h3,
               float* __restrict__ out) {
  __shared__ int cl[128];
  const int t = threadIdx.x;
  const int q = t & 127;                    // float4 index in row
  const int half = t >> 7;
  const int base = blockIdx.x * 128;
  if (t < 128) cl[t] = cids[base + t];
  __syncthreads();
  #pragma unroll 8
  for (int p = half; p < 128; p += 2) {
    int c = cl[p];
    v4f hv = ((const v4f*)(h3 + (size_t)c * HID))[q];
    v4f* dst = (v4f*)(out + (size_t)(base + p) * HID) + q;
    __builtin_nontemporal_store(hv, dst);
  }
}

// ---------------------------------------------------------------------------
extern "C" void kernel_launch(void* const* d_in, const int* in_sizes, int n_in,
                              void* d_out, int out_size, void* d_ws, size_t ws_size,
                              hipStream_t stream) {
  const float* x  = (const float*)d_in[0];
  const float* V0 = (const float*)d_in[1];
  const float* g0 = (const float*)d_in[2];
  const float* b0 = (const float*)d_in[3];
  const float* V1 = (const float*)d_in[4];
  const float* g1 = (const float*)d_in[5];
  const float* b1 = (const float*)d_in[6];
  const float* Wf = (const float*)d_in[7];
  const float* bf = (const float*)d_in[8];
  float* out = (float*)d_out;
  float* ws  = (float*)d_ws;

  size_t off = 0;
  float* psum   = ws + off; off += (size_t)NCASE * SEG * HID;   // 4 MB
  float* h3     = ws + off; off += NCASE * HID;
  float* scale0 = ws + off; off += 512;
  float* scale1 = ws + off; off += 512;
  int* iws = (int*)(ws + off);
  size_t ioff = 0;
  int* hist    = iws + ioff; ioff += NCASE * NB;
  int* cnt     = iws + ioff; ioff += NCASE;
  int* cids    = iws + ioff; ioff += NPTS;
  int* idxlist = iws + ioff; ioff += NPTS;

  k_hist     <<<dim3(NB), dim3(256), 0, stream>>>(x, hist, cids);
  k_scanbuild<<<dim3(NB), dim3(64), 0, stream>>>(hist, cids, idxlist, cnt);
  k_sum      <<<dim3(SEG, NCASE), dim3(128), 0, stream>>>(x, idxlist, cnt, psum);
  k_scale2   <<<dim3(1024), dim3(256), 0, stream>>>(V0, g0, V1, g1, scale0, scale1);
  k_mlp      <<<dim3(NCASE), dim3(512), 0, stream>>>(psum, cnt, V0, scale0, b0,
                                                     V1, scale1, b1, Wf, bf, h3);
  k_scatter  <<<dim3(NPTS / 128), dim3(256), 0, stream>>>(cids, h3, out);
}

// Round 9
// 199.872 us; speedup vs baseline: 1.4123x; 1.1948x over previous
//
#include <hip/hip_runtime.h>
#include <math.h>

#define NPTS   131072
#define INF    512
#define ROWF   513      // 512 features + 1 cid column
#define NCASE  64
#define HID    512
#define NB     256      // histogram chunks
#define CHUNK  512      // points per chunk
#define SEG    32       // segments per case for k_sum

typedef float v4f __attribute__((ext_vector_type(4)));

// ---------------------------------------------------------------------------
// K_hist: per-chunk cid histogram (LDS int atomics -> deterministic) + cid cache.
// hist stored transposed: hist[c*NB + b] so k_scan reads coalesced.
// ---------------------------------------------------------------------------
__global__ __launch_bounds__(256)
void k_hist(const float* __restrict__ x, int* __restrict__ hist,
            int* __restrict__ cids) {
  __shared__ int h[NCASE];
  const int t = threadIdx.x;
  const int b = blockIdx.x;
  if (t < NCASE) h[t] = 0;
  __syncthreads();
  const int base = b * CHUNK;
  for (int i = t; i < CHUNK; i += 256) {
    float cf = x[(size_t)(base + i) * ROWF + INF];
    int c = (int)(cf + 0.5f);
    cids[base + i] = c;
    atomicAdd(&h[c], 1);
  }
  __syncthreads();
  if (t < NCASE) hist[t * NB + b] = h[t];
}

// ---------------------------------------------------------------------------
// K_scan: per-case parallel exclusive scan over the 256 chunk histograms.
// ---------------------------------------------------------------------------
__global__ __launch_bounds__(256)
void k_scan(const int* __restrict__ hist, int* __restrict__ rel,
            int* __restrict__ cnt) {
  __shared__ int buf[NB];
  const int c = blockIdx.x;
  const int t = threadIdx.x;
  const int v = hist[c * NB + t];
  buf[t] = v;
  __syncthreads();
  for (int d = 1; d < NB; d <<= 1) {
    int u = (t >= d) ? buf[t - d] : 0;
    __syncthreads();
    buf[t] += u;
    __syncthreads();
  }
  rel[t * NCASE + c] = buf[t] - v;          // exclusive within case
  if (t == NB - 1) cnt[c] = buf[t];
}

// ---------------------------------------------------------------------------
// K_build: emit per-case point lists in point order (deterministic).
// ---------------------------------------------------------------------------
__global__ __launch_bounds__(64)
void k_build(const int* __restrict__ cids, const int* __restrict__ rel,
             const int* __restrict__ cnt, int* __restrict__ idxlist) {
  __shared__ int cidl[CHUNK];
  const int lane = threadIdx.x;
  const int b = blockIdx.x;
  for (int i = lane; i < CHUNK; i += 64) cidl[i] = cids[b * CHUNK + i];
  int lv = cnt[lane];
  int sc = lv;
  for (int d = 1; d < 64; d <<= 1) {
    int u = __shfl_up(sc, d, 64);
    if (lane >= d) sc += u;
  }
  const int base = sc - lv;                 // exclusive scan of cnt
  __syncthreads();
  int myoff = rel[b * NCASE + lane] + base;
  int rank = 0;
  for (int i = 0; i < CHUNK; ++i) {
    if (cidl[i] == lane) { idxlist[myoff + rank] = b * CHUNK + i; ++rank; }
  }
}

// ---------------------------------------------------------------------------
// K_sum v3: 4 waves per (segment, case) block; each wave owns a contiguous
// quarter of the segment's points. 2048 blocks x 4 waves = 32 waves/CU
// (max occupancy) -> 4x the in-flight bytes of the R5 config.
// Per wave: index batch loaded once, __shfl-broadcast; 4-point groups of
// 8x256B coalesced nontemporal row loads; register accumulate; LDS combine.
// ---------------------------------------------------------------------------
__global__ __launch_bounds__(256)
void k_sum(const float* __restrict__ x, const int* __restrict__ idxlist,
           const int* __restrict__ cnt, float* __restrict__ psum) {
  __shared__ float buf[4][HID];
  const int t = threadIdx.x;
  const int lane = t & 63;
  const int w = t >> 6;
  const int s = blockIdx.x;
  const int c = blockIdx.y;

  int lv = cnt[lane];
  int sc = lv;
  for (int d = 1; d < 64; d <<= 1) {
    int u = __shfl_up(sc, d, 64);
    if (lane >= d) sc += u;
  }
  const int bs = __shfl(sc - lv, c, 64);    // base[c]
  const int n  = __shfl(lv, c, 64);         // cnt[c]

  const int p0 = (s * n) / SEG;
  const int p1 = ((s + 1) * n) / SEG;
  const int m  = p1 - p0;
  const int q0 = (w * m) / 4;               // this wave's quarter
  const int q1 = ((w + 1) * m) / 4;

  float a[8];
  #pragma unroll
  for (int k = 0; k < 8; ++k) a[k] = 0.f;

  for (int j0 = q0; j0 < q1; j0 += 64) {
    const int nb = (q1 - j0 < 64) ? (q1 - j0) : 64;
    int iv = (lane < nb) ? idxlist[bs + p0 + j0 + lane] : 0;
    int jj = 0;
    for (; jj + 4 <= nb; jj += 4) {
      float v[4][8];
      #pragma unroll
      for (int u = 0; u < 4; ++u) {
        int idx = __shfl(iv, jj + u, 64);
        const float* r = x + (size_t)idx * ROWF + lane;
        #pragma unroll
        for (int k = 0; k < 8; ++k) v[u][k] = __builtin_nontemporal_load(r + 64 * k);
      }
      #pragma unroll
      for (int u = 0; u < 4; ++u) {
        #pragma unroll
        for (int k = 0; k < 8; ++k) a[k] += v[u][k];
      }
    }
    for (; jj < nb; ++jj) {
      int idx = __shfl(iv, jj, 64);
      const float* r = x + (size_t)idx * ROWF + lane;
      #pragma unroll
      for (int k = 0; k < 8; ++k) a[k] += __builtin_nontemporal_load(r + 64 * k);
    }
  }

  #pragma unroll
  for (int k = 0; k < 8; ++k) buf[w][lane + 64 * k] = a[k];
  __syncthreads();
  float* od = psum + ((size_t)c * SEG + s) * HID;
  for (int f = t; f < HID; f += 256)
    od[f] = (buf[0][f] + buf[1][f]) + (buf[2][f] + buf[3][f]);
}

// ---------------------------------------------------------------------------
// K_scale2: scale[row] = g[row] / ||V[row]|| for both layers in one launch.
// ---------------------------------------------------------------------------
__global__ __launch_bounds__(256)
void k_scale2(const float* __restrict__ V0, const float* __restrict__ g0,
              const float* __restrict__ V1, const float* __restrict__ g1,
              float* __restrict__ scale0, float* __restrict__ scale1) {
  __shared__ float red[256];
  const int row = blockIdx.x;               // 0..1023
  const int t   = threadIdx.x;
  const bool first = row < 512;
  const int r = first ? row : row - 512;
  const float* vr = (first ? V0 : V1) + (size_t)r * HID;
  float s = 0.f;
  for (int k = t; k < HID; k += 256) { float v = vr[k]; s += v * v; }
  red[t] = s;
  __syncthreads();
  for (int w = 128; w > 0; w >>= 1) {
    if (t < w) red[t] += red[t + w];
    __syncthreads();
  }
  if (t == 0) {
    float g = first ? g0[r] : g1[r];
    (first ? scale0 : scale1)[r] = g / sqrtf(red[0]);
  }
}

// ---------------------------------------------------------------------------
// K_layer: hout[n][o] = act( scale[o]*dot(hrow, W[o]) + bias[o] ).
// REDUCE: hrow = (sum over SEG psum segments)/cnt (fused h0 computation).
// ---------------------------------------------------------------------------
template <bool SILU, bool SCALED, bool REDUCE>
__global__ __launch_bounds__(256)
void k_layer(const float* __restrict__ hin, const float* __restrict__ W,
             const float* __restrict__ scale, const float* __restrict__ bias,
             const int* __restrict__ cnt, float* __restrict__ hout) {
  __shared__ float hrow[HID];
  const int n = blockIdx.y;
  const int t = threadIdx.x;
  const int o = blockIdx.x * 256 + t;
  if (REDUCE) {
    float inv = 1.f / fmaxf((float)cnt[n], 1.f);
    for (int f = t; f < HID; f += 256) {
      float s = 0.f;
      for (int seg = 0; seg < SEG; ++seg)
        s += hin[((size_t)n * SEG + seg) * HID + f];
      hrow[f] = s * inv;
    }
  } else {
    for (int f = t; f < HID; f += 256) hrow[f] = hin[(size_t)n * HID + f];
  }
  __syncthreads();
  const float* wr = W + (size_t)o * HID;
  float s0 = 0.f, s1 = 0.f, s2 = 0.f, s3 = 0.f;
  for (int k = 0; k < HID; k += 4) {
    float4 h4 = *(const float4*)&hrow[k];
    float4 w4 = *(const float4*)&wr[k];
    s0 += h4.x * w4.x; s1 += h4.y * w4.y;
    s2 += h4.z * w4.z; s3 += h4.w * w4.w;
  }
  float sdot = (s0 + s1) + (s2 + s3);
  float y = SCALED ? (sdot * scale[o] + bias[o]) : (sdot + bias[o]);
  if (SILU) y = y / (1.f + expf(-y));
  hout[(size_t)n * HID + o] = y;
}

// ---------------------------------------------------------------------------
// K_scatter: natural-order broadcast; nontemporal streaming stores.
// Each block owns 128 contiguous points (256 KB of sequential stores).
// ---------------------------------------------------------------------------
__global__ __launch_bounds__(256)
void k_scatter(const int* __restrict__ cids, const float* __restrict__ h3,
               float* __restrict__ out) {
  __shared__ int cl[128];
  const int t = threadIdx.x;
  const int q = t & 127;                    // float4 index in row
  const int half = t >> 7;
  const int base = blockIdx.x * 128;
  if (t < 128) cl[t] = cids[base + t];
  __syncthreads();
  #pragma unroll 8
  for (int p = half; p < 128; p += 2) {
    int c = cl[p];
    v4f hv = ((const v4f*)(h3 + (size_t)c * HID))[q];
    v4f* dst = (v4f*)(out + (size_t)(base + p) * HID) + q;
    __builtin_nontemporal_store(hv, dst);
  }
}

// ---------------------------------------------------------------------------
extern "C" void kernel_launch(void* const* d_in, const int* in_sizes, int n_in,
                              void* d_out, int out_size, void* d_ws, size_t ws_size,
                              hipStream_t stream) {
  const float* x  = (const float*)d_in[0];
  const float* V0 = (const float*)d_in[1];
  const float* g0 = (const float*)d_in[2];
  const float* b0 = (const float*)d_in[3];
  const float* V1 = (const float*)d_in[4];
  const float* g1 = (const float*)d_in[5];
  const float* b1 = (const float*)d_in[6];
  const float* Wf = (const float*)d_in[7];
  const float* bf = (const float*)d_in[8];
  float* out = (float*)d_out;
  float* ws  = (float*)d_ws;

  size_t off = 0;
  float* psum   = ws + off; off += (size_t)NCASE * SEG * HID;   // 4 MB
  float* h1     = ws + off; off += NCASE * HID;
  float* h2     = ws + off; off += NCASE * HID;
  float* h3     = ws + off; off += NCASE * HID;
  float* scale0 = ws + off; off += 512;
  float* scale1 = ws + off; off += 512;
  int* iws = (int*)(ws + off);
  size_t ioff = 0;
  int* hist    = iws + ioff; ioff += NCASE * NB;
  int* rel     = iws + ioff; ioff += NB * NCASE;
  int* cnt     = iws + ioff; ioff += NCASE;
  int* cids    = iws + ioff; ioff += NPTS;
  int* idxlist = iws + ioff; ioff += NPTS;

  k_scale2<<<dim3(1024), dim3(256), 0, stream>>>(V0, g0, V1, g1, scale0, scale1);
  k_hist  <<<dim3(NB), dim3(256), 0, stream>>>(x, hist, cids);
  k_scan  <<<dim3(NCASE), dim3(NB), 0, stream>>>(hist, rel, cnt);
  k_build <<<dim3(NB), dim3(64), 0, stream>>>(cids, rel, cnt, idxlist);
  k_sum   <<<dim3(SEG, NCASE), dim3(256), 0, stream>>>(x, idxlist, cnt, psum);
  k_layer<true,  true,  true ><<<dim3(2, NCASE), dim3(256), 0, stream>>>(psum, V0, scale0, b0, cnt, h1);
  k_layer<true,  true,  false><<<dim3(2, NCASE), dim3(256), 0, stream>>>(h1,   V1, scale1, b1, cnt, h2);
  k_layer<false, false, false><<<dim3(2, NCASE), dim3(256), 0, stream>>>(h2,   Wf, nullptr, bf, cnt, h3);
  k_scatter<<<dim3(NPTS / 128), dim3(256), 0, stream>>>(cids, h3, out);
}

// Round 10
// 191.508 us; speedup vs baseline: 1.4740x; 1.0437x over previous
//
#include <hip/hip_runtime.h>
#include <math.h>

#define NPTS   131072
#define INF    512
#define ROWF   513      // 512 features + 1 cid column
#define NCASE  64
#define HID    512
#define NB     256      // stream chunks
#define CHUNK  512      // points per chunk

typedef float v4f __attribute__((ext_vector_type(4)));

// ---------------------------------------------------------------------------
// K_stream: sequential-stream per-case accumulation. Block b owns rows
// [b*512, b*512+512). acc[64][512] in LDS (128 KB); thread t owns feature t
// for ALL cases -> exclusive RMW, deterministic order, conflict-free banks.
// 8-row prefetch groups keep ~2 KB/wave of sequential loads in flight while
// the LDS RMW chain of the previous group retires.
// Also emits cids (for scatter) and per-block counts (no global atomics).
// ---------------------------------------------------------------------------
__global__ __launch_bounds__(512)
void k_stream(const float* __restrict__ x, float* __restrict__ psum,
              float* __restrict__ pcnt, int* __restrict__ cids) {
  __shared__ float acc[NCASE * HID];   // 128 KB
  __shared__ int   cidl[CHUNK];        // 2 KB
  __shared__ int   cnth[NCASE];
  const int t = threadIdx.x;           // 0..511
  const int b = blockIdx.x;
  const int base = b * CHUNK;

  for (int i = t; i < NCASE * HID; i += 512) acc[i] = 0.f;
  if (t < NCASE) cnth[t] = 0;
  __syncthreads();

  // phase 0: one point per thread -> cid, global cid cache, LDS count
  {
    float cf = x[(size_t)(base + t) * ROWF + INF];
    int c = (int)(cf + 0.5f);
    cidl[t] = c;
    cids[base + t] = c;
    atomicAdd(&cnth[c], 1);
  }
  __syncthreads();

  const int f = t;                     // feature owned by this thread
  const float* xp = x + (size_t)base * ROWF + f;

  float v[8];
  #pragma unroll
  for (int j = 0; j < 8; ++j)
    v[j] = __builtin_nontemporal_load(xp + (size_t)j * ROWF);

  for (int p = 0; p < CHUNK; p += 8) {
    float nv[8];
    if (p + 8 < CHUNK) {
      #pragma unroll
      for (int j = 0; j < 8; ++j)
        nv[j] = __builtin_nontemporal_load(xp + (size_t)(p + 8 + j) * ROWF);
    }
    int cj[8];
    #pragma unroll
    for (int j = 0; j < 8; ++j) cj[j] = cidl[p + j];
    #pragma unroll
    for (int j = 0; j < 8; ++j) acc[cj[j] * HID + f] += v[j];
    #pragma unroll
    for (int j = 0; j < 8; ++j) v[j] = nv[j];
  }
  __syncthreads();

  float* od = psum + (size_t)b * NCASE * HID;
  for (int c = 0; c < NCASE; ++c)
    __builtin_nontemporal_store(acc[c * HID + f], &od[c * HID + f]);
  if (t < NCASE) pcnt[b * NCASE + t] = (float)cnth[t];
}

// ---------------------------------------------------------------------------
// K_h0: h0[c][f] = (sum_b psum[b][c][f]) / max(cnt[c],1).
// grid (64 cases, 4 feature-quarters) x 128 threads -> 256 blocks.
// ---------------------------------------------------------------------------
__global__ __launch_bounds__(128)
void k_h0(const float* __restrict__ psum, const float* __restrict__ pcnt,
          float* __restrict__ h0) {
  __shared__ float cs[128];
  const int c  = blockIdx.x;
  const int fq = blockIdx.y;
  const int t  = threadIdx.x;
  const int f  = fq * 128 + t;

  const float* p = psum + (size_t)c * HID + f;
  float s = 0.f;
  #pragma unroll 8
  for (int b = 0; b < NB; ++b) s += p[(size_t)b * NCASE * HID];

  cs[t] = pcnt[t * NCASE + c] + pcnt[(t + 128) * NCASE + c];
  __syncthreads();
  for (int w = 64; w > 0; w >>= 1) {
    if (t < w) cs[t] += cs[t + w];
    __syncthreads();
  }
  float cnt = fmaxf(cs[0], 1.f);
  h0[(size_t)c * HID + f] = s / cnt;
}

// ---------------------------------------------------------------------------
// K_scale2: scale[row] = g[row] / ||V[row]|| for both layers in one launch.
// ---------------------------------------------------------------------------
__global__ __launch_bounds__(256)
void k_scale2(const float* __restrict__ V0, const float* __restrict__ g0,
              const float* __restrict__ V1, const float* __restrict__ g1,
              float* __restrict__ scale0, float* __restrict__ scale1) {
  __shared__ float red[256];
  const int row = blockIdx.x;               // 0..1023
  const int t   = threadIdx.x;
  const bool first = row < 512;
  const int r = first ? row : row - 512;
  const float* vr = (first ? V0 : V1) + (size_t)r * HID;
  float s = 0.f;
  for (int k = t; k < HID; k += 256) { float v = vr[k]; s += v * v; }
  red[t] = s;
  __syncthreads();
  for (int w = 128; w > 0; w >>= 1) {
    if (t < w) red[t] += red[t + w];
    __syncthreads();
  }
  if (t == 0) {
    float g = first ? g0[r] : g1[r];
    (first ? scale0 : scale1)[r] = g / sqrtf(red[0]);
  }
}

// ---------------------------------------------------------------------------
// K_layer: hout[n][o] = act( scale[o]*dot(hin[n], W[o]) + bias[o] ).
// ---------------------------------------------------------------------------
template <bool SILU, bool SCALED>
__global__ __launch_bounds__(256)
void k_layer(const float* __restrict__ hin, const float* __restrict__ W,
             const float* __restrict__ scale, const float* __restrict__ bias,
             float* __restrict__ hout) {
  __shared__ float hrow[HID];
  const int n = blockIdx.y;
  const int t = threadIdx.x;
  const int o = blockIdx.x * 256 + t;
  for (int f = t; f < HID; f += 256) hrow[f] = hin[(size_t)n * HID + f];
  __syncthreads();
  const float* wr = W + (size_t)o * HID;
  float s0 = 0.f, s1 = 0.f, s2 = 0.f, s3 = 0.f;
  for (int k = 0; k < HID; k += 4) {
    float4 h4 = *(const float4*)&hrow[k];
    float4 w4 = *(const float4*)&wr[k];
    s0 += h4.x * w4.x; s1 += h4.y * w4.y;
    s2 += h4.z * w4.z; s3 += h4.w * w4.w;
  }
  float sdot = (s0 + s1) + (s2 + s3);
  float y = SCALED ? (sdot * scale[o] + bias[o]) : (sdot + bias[o]);
  if (SILU) y = y / (1.f + expf(-y));
  hout[(size_t)n * HID + o] = y;
}

// ---------------------------------------------------------------------------
// K_scatter: natural-order broadcast; nontemporal streaming stores.
// Each block owns 128 contiguous points (256 KB of sequential stores).
// ---------------------------------------------------------------------------
__global__ __launch_bounds__(256)
void k_scatter(const int* __restrict__ cids, const float* __restrict__ h3,
               float* __restrict__ out) {
  __shared__ int cl[128];
  const int t = threadIdx.x;
  const int q = t & 127;                    // float4 index in row
  const int half = t >> 7;
  const int base = blockIdx.x * 128;
  if (t < 128) cl[t] = cids[base + t];
  __syncthreads();
  #pragma unroll 8
  for (int p = half; p < 128; p += 2) {
    int c = cl[p];
    v4f hv = ((const v4f*)(h3 + (size_t)c * HID))[q];
    v4f* dst = (v4f*)(out + (size_t)(base + p) * HID) + q;
    __builtin_nontemporal_store(hv, dst);
  }
}

// ---------------------------------------------------------------------------
extern "C" void kernel_launch(void* const* d_in, const int* in_sizes, int n_in,
                              void* d_out, int out_size, void* d_ws, size_t ws_size,
                              hipStream_t stream) {
  const float* x  = (const float*)d_in[0];
  const float* V0 = (const float*)d_in[1];
  const float* g0 = (const float*)d_in[2];
  const float* b0 = (const float*)d_in[3];
  const float* V1 = (const float*)d_in[4];
  const float* g1 = (const float*)d_in[5];
  const float* b1 = (const float*)d_in[6];
  const float* Wf = (const float*)d_in[7];
  const float* bf = (const float*)d_in[8];
  float* out = (float*)d_out;
  float* ws  = (float*)d_ws;

  size_t off = 0;
  float* psum   = ws + off; off += (size_t)NB * NCASE * HID;    // 32 MB
  float* pcnt   = ws + off; off += NB * NCASE;
  float* h0     = ws + off; off += NCASE * HID;
  float* h1     = ws + off; off += NCASE * HID;
  float* h2     = ws + off; off += NCASE * HID;
  float* h3     = ws + off; off += NCASE * HID;
  float* scale0 = ws + off; off += 512;
  float* scale1 = ws + off; off += 512;
  int*   cids   = (int*)(ws + off); off += NPTS;

  k_scale2<<<dim3(1024), dim3(256), 0, stream>>>(V0, g0, V1, g1, scale0, scale1);
  k_stream<<<dim3(NB), dim3(512), 0, stream>>>(x, psum, pcnt, cids);
  k_h0    <<<dim3(NCASE, 4), dim3(128), 0, stream>>>(psum, pcnt, h0);
  k_layer<true,  true ><<<dim3(2, NCASE), dim3(256), 0, stream>>>(h0, V0, scale0, b0, h1);
  k_layer<true,  true ><<<dim3(2, NCASE), dim3(256), 0, stream>>>(h1, V1, scale1, b1, h2);
  k_layer<false, false><<<dim3(2, NCASE), dim3(256), 0, stream>>>(h2, Wf, nullptr, bf, h3);
  k_scatter<<<dim3(NPTS / 128), dim3(256), 0, stream>>>(cids, h3, out);
}